// Round 6
// baseline (3437.165 us; speedup 1.0000x reference)
//
#include <hip/hip_runtime.h>

typedef __attribute__((ext_vector_type(8))) short short8;
typedef __attribute__((ext_vector_type(4))) float floatx4;

#define DIN  512
#define HSZ  1024
#define G4   4096
#define KTOT 1536
#define BQ   256
#define TT   256

#define MFMA __builtin_amdgcn_mfma_f32_16x16x32_bf16

__device__ __forceinline__ unsigned short f2bf(float f){
  unsigned int u = __float_as_uint(f);
  u += 0x7fffu + ((u >> 16) & 1u);
  return (unsigned short)(u >> 16);
}
__device__ __forceinline__ unsigned int pack2(float a, float b){
  return (unsigned int)f2bf(a) | ((unsigned int)f2bf(b) << 16);
}

// ---------------- prep kernels ----------------
__global__ void prep_wcat(const float* __restrict__ wx, const float* __restrict__ wh,
                          const float* __restrict__ bx, const float* __restrict__ bh,
                          unsigned short* __restrict__ Wcat, float* __restrict__ bias){
  int gid = blockIdx.x * blockDim.x + threadIdx.x;
  int idx = gid * 8;
  int g = idx / KTOT;
  int k = idx - g * KTOT;
  const float* src = (k < DIN) ? (wx + (size_t)g * DIN + k)
                               : (wh + (size_t)g * HSZ + (k - DIN));
  float4 f0 = *(const float4*)(src);
  float4 f1 = *(const float4*)(src + 4);
  uint4 v = make_uint4(pack2(f0.x,f0.y), pack2(f0.z,f0.w), pack2(f1.x,f1.y), pack2(f1.z,f1.w));
  *(uint4*)(Wcat + (size_t)g * KTOT + k) = v;
  if (gid < G4) bias[gid] = bx[gid] + bh[gid];
}

// W_x2h -> WxP[kb 0..63][col 0..4095][8] bf16 (coalesced B-frag layout)
__global__ void prep_wxp(const float* __restrict__ wx, unsigned short* __restrict__ WxP){
  int gid = blockIdx.x * 256 + threadIdx.x;   // 4096*64
  int col = gid >> 6;
  int kb  = gid & 63;
  const float* src = wx + (size_t)col * DIN + kb * 8;
  float4 f0 = *(const float4*)(src);
  float4 f1 = *(const float4*)(src + 4);
  uint4 v = make_uint4(pack2(f0.x,f0.y), pack2(f0.z,f0.w), pack2(f1.x,f1.y), pack2(f1.z,f1.w));
  *(uint4*)(WxP + ((size_t)kb * G4 + col) * 8) = v;
}

__global__ void prep_wfc(const float* __restrict__ wfc, unsigned short* __restrict__ Wfcb){
  int gid = blockIdx.x * blockDim.x + threadIdx.x;
  int idx = gid * 8;
  int n = idx >> 10;
  int k = idx & 1023;
  uint4 v;
  if (n < 1000){
    const float* src = wfc + (size_t)n * 1024 + k;
    float4 f0 = *(const float4*)(src);
    float4 f1 = *(const float4*)(src + 4);
    v = make_uint4(pack2(f0.x,f0.y), pack2(f0.z,f0.w), pack2(f1.x,f1.y), pack2(f1.z,f1.w));
  } else {
    v = make_uint4(0u, 0u, 0u, 0u);
  }
  *(uint4*)(Wfcb + idx) = v;
}

// x[b][t][d] fp32 -> xbf[t][b][d] bf16
__global__ void prep_x(const float* __restrict__ x, unsigned short* __restrict__ xbf){
  int gid = blockIdx.x * 256 + threadIdx.x;
  int d8 = gid & 63;
  int b  = (gid >> 6) & 255;
  int t  = gid >> 14;
  const float* src = x + (((size_t)b * TT) + t) * DIN + d8 * 8;
  float4 f0 = *(const float4*)(src);
  float4 f1 = *(const float4*)(src + 4);
  uint4 v = make_uint4(pack2(f0.x,f0.y), pack2(f0.z,f0.w), pack2(f1.x,f1.y), pack2(f1.z,f1.w));
  *(uint4*)(xbf + (((size_t)t * BQ) + b) * DIN + d8 * 8) = v;
}

__global__ void init_misc(unsigned int* __restrict__ h0w, unsigned int* __restrict__ flags, int nflags){
  int gid = blockIdx.x * 256 + threadIdx.x;
  if (gid < 131072) h0w[gid] = 0u;   // hseq[0]: 256*1024 bf16
  if (gid < nflags) flags[gid] = 0u;
}

// ---------------- persistent LSTM ----------------
// 256 blocks x 512 threads. bg = bx>>6 (batch quarter, 64 rows) -> 4 INDEPENDENT
// chains of 64 blocks. Block: 16 units (64 gate-cols) x 64 rows.
// W_h2h slice (64 cols x 1024 K) in LDS (128 KB). x-part (K=512) computed for
// step t+1 during post-publish slack, accumulated in registers, W_x2h streamed
// from WxP (L2). Barrier: RMW-free flag zone per (t,bg), 1 store / 1-round poll.
__global__ __launch_bounds__(512, 2)
void lstm_persist(const unsigned short* __restrict__ xbf,
                  const unsigned short* __restrict__ Wcat,
                  const unsigned short* __restrict__ WxP,
                  const float* __restrict__ bias,
                  unsigned short* __restrict__ hseq,   // [257][256][1024] bf16
                  unsigned int* __restrict__ flags){   // [257][4][64] u32
  extern __shared__ char smem[];
  char*  Ws  = smem;                      // 64 * 2048 = 131072
  float* Gt  = (float*)(smem + 131072);   // 64 * 68 * 4 = 17408
  float* Bls = (float*)(smem + 148480);   // 64 floats

  const int tid  = threadIdx.x;
  const int bx   = blockIdx.x;
  const int bg   = bx >> 6;          // 0..3 batch quarter
  const int hb6  = bx & 63;          // 0..63 unit-block
  const int b0   = bg << 6;
  const int u0   = hb6 << 4;         // 16 units
  const int lane = tid & 63;
  const int w    = tid >> 6;
  const int kg   = w & 1;            // K half
  const int cg   = (w >> 1) & 1;     // col half (32 cols)
  const int rg   = (w >> 2) & 1;     // row half (32 rows)

  // ---- one-time: W_h2h slice -> LDS (XOR swizzled), bias -> LDS ----
  {
    int c  = tid >> 3;               // 0..63: col = gate*16 + unit
    int ch = tid & 7;                // 8 threads/col, 256 B each
    int g = c >> 4, uu = c & 15;
    const char* src = (const char*)(Wcat + (size_t)(g * HSZ + u0 + uu) * KTOT + DIN);
    char* dst = Ws + c * 2048;
    int xr = (c & 7) << 4;
    #pragma unroll
    for (int q = 0; q < 16; ++q){
      int off = ch * 256 + q * 16;
      *(uint4*)(dst + (off ^ xr)) = *(const uint4*)(src + off);
    }
    if (tid < 64) Bls[tid] = bias[(size_t)(tid >> 4) * HSZ + u0 + (tid & 15)];
  }
  __syncthreads();

  const int kq8 = (lane >> 4) * 8;
  const int c0  = cg * 32 + (lane & 15);
  const int c1  = c0 + 16;
  const char* bp0 = Ws + c0 * 2048; const int xr0 = (c0 & 7) << 4;
  const char* bp1 = Ws + c1 * 2048; const int xr1 = (c1 & 7) << 4;
  const int gcol0 = (c0 >> 4) * HSZ + u0 + (lane & 15);
  const int gcol1 = (c1 >> 4) * HSZ + u0 + (lane & 15);
  const int arow  = b0 + rg * 32 + (lane & 15);   // +16 for rf=1

  // elementwise mapping (fixed per thread; c-state in regs)
  const int er = tid >> 3;           // 0..63 row
  const int up = (tid & 7) * 2;      // units up, up+1
  float cst0 = 0.f, cst1 = 0.f;

  floatx4 xacc[2][2];                // x-part partial for the CURRENT step

  auto compute_x = [&](int t){
    const unsigned short* xr0p = xbf + ((size_t)t * BQ + arow) * DIN + kg * 256 + kq8;
    const unsigned short* xr1p = xr0p + 16 * DIN;
    short8 XA0[8], XA1[8], XB0[8], XB1[8];
    #pragma unroll
    for (int j = 0; j < 8; ++j){
      XA0[j] = *(const short8*)(xr0p + j * 32);
      XA1[j] = *(const short8*)(xr1p + j * 32);
      int kb = kg * 32 + j * 4 + (lane >> 4);
      XB0[j] = *(const short8*)(WxP + ((size_t)kb * G4 + gcol0) * 8);
      XB1[j] = *(const short8*)(WxP + ((size_t)kb * G4 + gcol1) * 8);
    }
    __builtin_amdgcn_sched_barrier(0);
    #pragma unroll
    for (int rf = 0; rf < 2; ++rf)
      #pragma unroll
      for (int cf = 0; cf < 2; ++cf)
        xacc[rf][cf] = (floatx4){0.f,0.f,0.f,0.f};
    #pragma unroll
    for (int j = 0; j < 8; ++j){
      xacc[0][0] = MFMA(XA0[j], XB0[j], xacc[0][0], 0, 0, 0);
      xacc[0][1] = MFMA(XA0[j], XB1[j], xacc[0][1], 0, 0, 0);
      xacc[1][0] = MFMA(XA1[j], XB0[j], xacc[1][0], 0, 0, 0);
      xacc[1][1] = MFMA(XA1[j], XB1[j], xacc[1][1], 0, 0, 0);
    }
  };

  compute_x(0);

  for (int t = 0; t < TT; ++t){
    const unsigned short* hin  = hseq + (size_t)t * (BQ * HSZ);
    unsigned short*       hout = hseq + (size_t)(t + 1) * (BQ * HSZ);

    // ===== wait: h[t] flags (64 producers, 1-round 4-line poll) =====
    if (t > 0){
      if (tid < 64){
        const unsigned int* fp = flags + (((size_t)t * 4 + bg) << 6);
        while (true){
          unsigned int v = __hip_atomic_load(fp + lane, __ATOMIC_RELAXED, __HIP_MEMORY_SCOPE_AGENT);
          if (__ballot(v != 0u) == ~0ull) break;
          __builtin_amdgcn_s_sleep(1);
        }
      }
      __syncthreads();
      asm volatile("" ::: "memory");
    }

    // ===== h-part GEMM: K=512/wave, 32 A-loads batched, B LDS depth-2 =====
    floatx4 hacc[2][2];
    #pragma unroll
    for (int rf = 0; rf < 2; ++rf)
      #pragma unroll
      for (int cf = 0; cf < 2; ++cf)
        hacc[rf][cf] = (floatx4){0.f,0.f,0.f,0.f};
    {
      const unsigned short* hr0 = hin + (size_t)arow * HSZ + kg * 512 + kq8;
      const unsigned short* hr1 = hr0 + 16 * HSZ;
      short8 HA0[16], HA1[16];
      #pragma unroll
      for (int p = 0; p < 16; ++p){
        HA0[p] = *(const short8*)(hr0 + p * 32);
        HA1[p] = *(const short8*)(hr1 + p * 32);
      }
      __builtin_amdgcn_sched_barrier(0);
      const int kb2 = kg * 1024 + kq8 * 2;
      short8 B0[2], B1[2];
      B0[0] = *(const short8*)(bp0 + ((kb2     ) ^ xr0));
      B1[0] = *(const short8*)(bp1 + ((kb2     ) ^ xr1));
      B0[1] = *(const short8*)(bp0 + ((kb2 + 64) ^ xr0));
      B1[1] = *(const short8*)(bp1 + ((kb2 + 64) ^ xr1));
      #pragma unroll
      for (int j = 0; j < 16; ++j){
        const int sl = j & 1;
        short8 b0v = B0[sl], b1v = B1[sl];
        if (j < 14){
          int bb = kb2 + (j + 2) * 64;
          B0[sl] = *(const short8*)(bp0 + (bb ^ xr0));
          B1[sl] = *(const short8*)(bp1 + (bb ^ xr1));
        }
        hacc[0][0] = MFMA(HA0[j], b0v, hacc[0][0], 0, 0, 0);
        hacc[0][1] = MFMA(HA0[j], b1v, hacc[0][1], 0, 0, 0);
        hacc[1][0] = MFMA(HA1[j], b0v, hacc[1][0], 0, 0, 0);
        hacc[1][1] = MFMA(HA1[j], b1v, hacc[1][1], 0, 0, 0);
      }
    }

    // ===== gates = hacc + xacc, two-phase kg reduction in Gt =====
    if (kg == 0){
      int grow = rg * 32 + (lane >> 4) * 4;
      #pragma unroll
      for (int rf = 0; rf < 2; ++rf){
        floatx4 gv0 = hacc[rf][0] + xacc[rf][0];
        floatx4 gv1 = hacc[rf][1] + xacc[rf][1];
        #pragma unroll
        for (int r = 0; r < 4; ++r){
          Gt[(grow + rf * 16 + r) * 68 + c0] = gv0[r];
          Gt[(grow + rf * 16 + r) * 68 + c1] = gv1[r];
        }
      }
    }
    __syncthreads();
    if (kg == 1){
      int grow = rg * 32 + (lane >> 4) * 4;
      #pragma unroll
      for (int rf = 0; rf < 2; ++rf){
        floatx4 gv0 = hacc[rf][0] + xacc[rf][0];
        floatx4 gv1 = hacc[rf][1] + xacc[rf][1];
        #pragma unroll
        for (int r = 0; r < 4; ++r){
          Gt[(grow + rf * 16 + r) * 68 + c0] += gv0[r];
          Gt[(grow + rf * 16 + r) * 68 + c1] += gv1[r];
        }
      }
    }
    __syncthreads();

    // ===== elementwise: 1 row x 2 units per thread; h sc1-store =====
    {
      const float* gr = Gt + er * 68;
      float gi0 = gr[     up] + Bls[     up];
      float gf0 = gr[16 + up] + Bls[16 + up];
      float gg0 = gr[32 + up] + Bls[32 + up];
      float go0 = gr[48 + up] + Bls[48 + up];
      float gi1 = gr[     up + 1] + Bls[     up + 1];
      float gf1 = gr[16 + up + 1] + Bls[16 + up + 1];
      float gg1 = gr[32 + up + 1] + Bls[32 + up + 1];
      float go1 = gr[48 + up + 1] + Bls[48 + up + 1];

      float iv0 = 1.f / (1.f + __expf(-gi0));
      float fv0 = 1.f / (1.f + __expf(-gf0));
      float e20 = __expf(-2.f * fmaxf(fminf(gg0, 30.f), -30.f));
      float gv0 = (1.f - e20) / (1.f + e20);
      float ov0 = 1.f / (1.f + __expf(-go0));
      float cn0 = cst0 * fv0 + iv0 * gv0;
      cst0 = cn0;
      float ec0 = __expf(-2.f * fmaxf(fminf(cn0, 30.f), -30.f));
      float hv0 = ov0 * (1.f - ec0) / (1.f + ec0);

      float iv1 = 1.f / (1.f + __expf(-gi1));
      float fv1 = 1.f / (1.f + __expf(-gf1));
      float e21 = __expf(-2.f * fmaxf(fminf(gg1, 30.f), -30.f));
      float gv1 = (1.f - e21) / (1.f + e21);
      float ov1 = 1.f / (1.f + __expf(-go1));
      float cn1 = cst1 * fv1 + iv1 * gv1;
      cst1 = cn1;
      float ec1 = __expf(-2.f * fmaxf(fminf(cn1, 30.f), -30.f));
      float hv1 = ov1 * (1.f - ec1) / (1.f + ec1);

      __hip_atomic_store((unsigned int*)(hout + (size_t)(b0 + er) * HSZ + u0 + up),
                         pack2(hv0, hv1), __ATOMIC_RELAXED, __HIP_MEMORY_SCOPE_AGENT);
    }
    __syncthreads();  // drains all waves' h-stores before the flag

    // ===== arrive: one RMW-free flag store =====
    if (tid == 0)
      __hip_atomic_store(&flags[(((size_t)(t + 1) * 4 + bg) << 6) + hb6], 1u,
                         __ATOMIC_RELAXED, __HIP_MEMORY_SCOPE_AGENT);

    // ===== slack: x-part for t+1 (off the critical chain) =====
    if (t + 1 < TT) compute_x(t + 1);
  }
}

// ---------------- final FC: out[256][1000] = h @ Wfc^T + b ----------------
__global__ __launch_bounds__(256, 1)
void fc_kernel(const unsigned short* __restrict__ h, const unsigned short* __restrict__ wfc,
               const float* __restrict__ bfc, float* __restrict__ out){
  int bx = blockIdx.x, tid = threadIdx.x;
  int wave = tid >> 6, lane = tid & 63;
  int row0 = (bx >> 4) * 64 + wave * 16;
  int col0 = (bx & 15) * 64;
  int lr = lane & 15, lk = (lane >> 4) * 8;
  floatx4 acc[4] = {{0.f,0.f,0.f,0.f},{0.f,0.f,0.f,0.f},{0.f,0.f,0.f,0.f},{0.f,0.f,0.f,0.f}};
  #pragma unroll 4
  for (int ks = 0; ks < 32; ++ks){
    int k = ks * 32 + lk;
    short8 a = *(const short8*)(h + (size_t)(row0 + lr) * 1024 + k);
    #pragma unroll
    for (int fj = 0; fj < 4; ++fj){
      short8 b = *(const short8*)(wfc + (size_t)(col0 + fj * 16 + lr) * 1024 + k);
      acc[fj] = MFMA(a, b, acc[fj], 0, 0, 0);
    }
  }
  #pragma unroll
  for (int fj = 0; fj < 4; ++fj){
    int col = col0 + fj * 16 + lr;
    if (col < 1000){
      #pragma unroll
      for (int r = 0; r < 4; ++r){
        int row = row0 + (lane >> 4) * 4 + r;
        out[(size_t)row * 1000 + col] = acc[fj][r] + bfc[col];
      }
    }
  }
}

// ---------------- launch ----------------
extern "C" void kernel_launch(void* const* d_in, const int* in_sizes, int n_in,
                              void* d_out, int out_size, void* d_ws, size_t ws_size,
                              hipStream_t stream){
  const float* x    = (const float*)d_in[0];
  const float* wx2h = (const float*)d_in[1];
  const float* bx2h = (const float*)d_in[2];
  const float* wh2h = (const float*)d_in[3];
  const float* bh2h = (const float*)d_in[4];
  const float* wfc  = (const float*)d_in[5];
  const float* bfc  = (const float*)d_in[6];
  float* out = (float*)d_out;
  char* ws = (char*)d_ws;

  // ws layout (bytes)
  unsigned short* Wcat  = (unsigned short*)(ws + 0);             //  12,582,912
  unsigned short* Wfcb  = (unsigned short*)(ws + 12582912);      //   2,097,152
  float*          bias  = (float*)         (ws + 14680064);      //      16,384
  unsigned short* WxP   = (unsigned short*)(ws + 14696448);      //   4,194,304
  unsigned short* xbf   = (unsigned short*)(ws + 18890752);      //  67,108,864
  unsigned short* hseq  = (unsigned short*)(ws + 85999616);      // 134,742,016 (257 x 512KB)
  unsigned int*   flags = (unsigned int*)  (ws + 220741632);     //     263,168 (257*4*256B)
  // total ~221 MB

  (void)hipFuncSetAttribute((const void*)lstm_persist,
                            hipFuncAttributeMaxDynamicSharedMemorySize, 148736);

  hipLaunchKernelGGL(prep_wcat, dim3(3072), dim3(256), 0, stream, wx2h, wh2h, bx2h, bh2h, Wcat, bias);
  hipLaunchKernelGGL(prep_wxp,  dim3(1024), dim3(256), 0, stream, wx2h, WxP);
  hipLaunchKernelGGL(prep_wfc,  dim3(512),  dim3(256), 0, stream, wfc, Wfcb);
  hipLaunchKernelGGL(prep_x,    dim3(16384),dim3(256), 0, stream, x, xbf);
  hipLaunchKernelGGL(init_misc, dim3(512),  dim3(256), 0, stream,
                     (unsigned int*)hseq, flags, (int)(263168 / 4));

  hipLaunchKernelGGL(lstm_persist, dim3(256), dim3(512), 148736, stream,
                     xbf, Wcat, WxP, bias, hseq, flags);

  // final h = hseq[256]
  hipLaunchKernelGGL(fc_kernel, dim3(64), dim3(256), 0, stream,
                     hseq + (size_t)256 * BQ * HSZ, Wfcb, bfc, out);
}